// Round 2
// baseline (456.144 us; speedup 1.0000x reference)
//
#include <hip/hip_runtime.h>

// LSTM cell: fp32 inputs, fp32 output (bf16-lenient compare).
// gates[B,3H] = x@Wx^T + h@Wh^T + b; new_c = sig(gf)*c + sig(gi)*tanh(gg).
// M=16384, N=1024 x 3 gates, K=2048 (x||h fused).
//
// v3: fragment-ordered workspace + counted-vmcnt 4-deep half-tile pipeline.
//  1) pack_a: x||h -> bf16 ws in MFMA A-fragment lane order
//     [mt(128)][kt(32)][half(2)][frag(8)=r32*2+ks2][lane(64)][16B]
//  2) pack_w: weights -> bf16 ws in MFMA B-fragment lane order
//     [nt(16)][kt(32)][half(2)][frag(12)=(g*2+n32)*2+ks2][lane(64)][16B]
//  3) lstm_gemm: ring of 4 LDS half-buffers (20KB each), stage-ahead-3,
//     s_waitcnt vmcnt(10) + raw s_barrier per phase (never vmcnt(0) in loop),
//     all ds_read_b128 are wave-linear 1KB (base + lane*16 + imm): zero bank
//     conflicts by construction. setprio(1) around MFMA cluster.

#define HS      1024
#define K_TOTAL 2048
#define NHALF   64            // 2048 / 32
#define AH_B    8192          // A half-tile bytes: 128 rows x 32 k x 2B
#define WH_B    12288         // W half-tile bytes: 3 x 64 x 32 x 2B
#define BUFB    20480         // AH_B + WH_B
#define A_MT_B  524288        // per-mt A panel bytes (64 half-tiles)
#define W_NT_B  786432        // per-nt W panel bytes

typedef __bf16 bf16;
typedef bf16  bf16x4  __attribute__((ext_vector_type(4)));
typedef bf16  bf16x8  __attribute__((ext_vector_type(8)));
typedef float f32x4   __attribute__((ext_vector_type(4)));
typedef float f32x16  __attribute__((ext_vector_type(16)));

#define WAITVM(N) asm volatile("s_waitcnt vmcnt(" #N ")" ::: "memory")

// async 16B global -> LDS (wave-uniform LDS base + implicit lane*16)
__device__ __forceinline__ void cp16(void* lds, const void* g) {
  __builtin_amdgcn_global_load_lds(
      (const __attribute__((address_space(1))) void*)g,
      (__attribute__((address_space(3))) void*)lds, 16, 0, 0);
}

__device__ __forceinline__ bf16x8 cvt8(const f32x4 v0, const f32x4 v1) {
  bf16x8 o;
  o[0] = (bf16)v0[0]; o[1] = (bf16)v0[1]; o[2] = (bf16)v0[2]; o[3] = (bf16)v0[3];
  o[4] = (bf16)v1[0]; o[5] = (bf16)v1[1]; o[6] = (bf16)v1[2]; o[7] = (bf16)v1[3];
  return o;
}

// ---------------------------------------------------------------------------
// pack_a: each thread produces one 16B fragment chunk (fully coalesced write);
// source read is 32B f32 per thread, block-local 128B-line reuse via L1.
__global__ __launch_bounds__(256) void pack_a(const float* __restrict__ x,
                                              const float* __restrict__ h,
                                              bf16* __restrict__ Aws) {
  const unsigned gt   = blockIdx.x * 256 + threadIdx.x;
  const unsigned byte = gt * 16;
  const unsigned mt   = byte >> 19;
  const unsigned kt   = (byte >> 14) & 31u;
  const unsigned half = (byte >> 13) & 1u;
  const unsigned frag = (byte >> 10) & 7u;
  const unsigned lane = (byte >> 4) & 63u;
  const unsigned m  = mt * 128 + (frag >> 1) * 32 + (lane & 31u);
  const unsigned ks = half * 2 + (frag & 1u);
  const unsigned k  = kt * 64 + ks * 16 + (lane >> 5) * 8;
  const float* src = (k < 1024u) ? (x + (size_t)m * HS + k)
                                 : (h + (size_t)m * HS + (k - 1024u));
  const f32x4 v0 = *(const f32x4*)src;
  const f32x4 v1 = *(const f32x4*)(src + 4);
  *(bf16x8*)((char*)Aws + byte) = cvt8(v0, v1);
}

__global__ __launch_bounds__(256) void pack_w(
    const float* __restrict__ w_ii, const float* __restrict__ w_hi,
    const float* __restrict__ w_if, const float* __restrict__ w_hf,
    const float* __restrict__ w_ig, const float* __restrict__ w_hg,
    bf16* __restrict__ Wws) {
  const unsigned gt   = blockIdx.x * 256 + threadIdx.x;
  const unsigned byte = gt * 16;
  const unsigned nt = byte / 786432u;
  const unsigned r  = byte % 786432u;
  const unsigned kt = r / 24576u;
  const unsigned r2 = r % 24576u;
  const unsigned half = (r2 >= 12288u) ? 1u : 0u;
  const unsigned r3 = r2 - half * 12288u;
  const unsigned frag = r3 >> 10;          // 0..11 = (g*2+n32)*2+ks2
  const unsigned lane = (r3 >> 4) & 63u;
  const unsigned g    = frag >> 2;
  const unsigned n32  = (frag >> 1) & 1u;
  const unsigned ks   = half * 2 + (frag & 1u);
  const unsigned n = nt * 64 + n32 * 32 + (lane & 31u);
  const unsigned k = kt * 64 + ks * 16 + (lane >> 5) * 8;
  const float* wx = (g == 0) ? w_ii : (g == 1) ? w_if : w_ig;
  const float* wh = (g == 0) ? w_hi : (g == 1) ? w_hf : w_hg;
  const float* src = (k < 1024u) ? (wx + (size_t)n * HS + k)
                                 : (wh + (size_t)n * HS + (k - 1024u));
  const f32x4 v0 = *(const f32x4*)src;
  const f32x4 v1 = *(const f32x4*)(src + 4);
  *(bf16x8*)((char*)Wws + byte) = cvt8(v0, v1);
}

// ---------------------------------------------------------------------------
// GEMM: block = 128M x 64N x 3 gates, 256 thr = 4 waves (2x2),
// wave = 64M x 32N x 3. Phase = K32 half-tile, 64 phases, ring of 4 bufs.
__global__ __launch_bounds__(256, 2) void lstm_gemm(
    const bf16* __restrict__ Aws, const bf16* __restrict__ Wws,
    const float* __restrict__ c,
    const float* __restrict__ b_ii, const float* __restrict__ b_hi,
    const float* __restrict__ b_if, const float* __restrict__ b_hf,
    const float* __restrict__ b_ig, const float* __restrict__ b_hg,
    float* __restrict__ out)
{
  __shared__ __align__(16) char smem[4 * BUFB];   // 80 KB

  const int tid  = threadIdx.x;
  const int lane = tid & 63;
  const int wave = tid >> 6;

  // XCD-bijective swizzle: 2048 wgs, 8 XCDs, 256 contiguous wgs per XCD.
  const int bid = blockIdx.x;
  const int wg  = (bid & 7) * 256 + (bid >> 3);
  const int nt  = wg & 15;     // nt-minor: consecutive wgs share A-panel
  const int mt  = wg >> 4;
  const int m0  = mt * 128;
  const int n0  = nt * 64;
  const int wm  = (wave & 1) * 64;
  const int wn  = (wave >> 1) * 32;
  const int r32a = (wave & 1) * 2;   // A fragment row-group (0 or 2)
  const int n32  = (wave >> 1);      // W fragment n-group (0 or 1)

  const char* Apan = (const char*)Aws + (size_t)mt * A_MT_B;
  const char* Wpan = (const char*)Wws + (size_t)nt * W_NT_B;

  const int aoff = wave * 2048;   // 2 A-chunks per wave
  const int boff = wave * 3072;   // 3 W-chunks per wave
  const int lb   = lane * 16;

  f32x16 acc[3][2] = {};

  // stage half-tile h into ring buffer `buf` (5 global_load_lds / thread-wave)
  auto stage = [&](int h, int buf) {
    char* dst = smem + buf * BUFB;
    const char* sa = Apan + (size_t)h * AH_B + aoff + lb;
    const char* sw = Wpan + (size_t)h * WH_B + boff + lb;
    cp16(dst + aoff,        sa);
    cp16(dst + aoff + 1024, sa + 1024);
    char* dw = dst + AH_B + boff;
    cp16(dw,        sw);
    cp16(dw + 1024, sw + 1024);
    cp16(dw + 2048, sw + 2048);
  };

  // prologue: 3 half-tiles in flight
  stage(0, 0);
  stage(1, 1);
  stage(2, 2);

#pragma unroll 4
  for (int h = 0; h < NHALF; ++h) {
    // wait for half-tile h (oldest 5 loads); h+1,h+2 stay in flight
    if (h < NHALF - 2)      { WAITVM(10); }
    else if (h == NHALF - 2){ WAITVM(5);  }
    else                    { WAITVM(0);  }
    __builtin_amdgcn_s_barrier();

    if (h < NHALF - 3) stage(h + 3, (h + 3) & 3);

    const char* base = smem + (h & 3) * BUFB;
    const char* Ab = base + lb;
    const char* Wb = base + AH_B + lb;

#pragma unroll
    for (int ks2 = 0; ks2 < 2; ++ks2) {
      const bf16x8 a0 = *(const bf16x8*)(Ab + (((r32a    ) * 2 + ks2) << 10));
      const bf16x8 a1 = *(const bf16x8*)(Ab + (((r32a + 1) * 2 + ks2) << 10));
      const bf16x8 b0 = *(const bf16x8*)(Wb + (((0 * 2 + n32) * 2 + ks2) << 10));
      const bf16x8 b1 = *(const bf16x8*)(Wb + (((1 * 2 + n32) * 2 + ks2) << 10));
      const bf16x8 b2 = *(const bf16x8*)(Wb + (((2 * 2 + n32) * 2 + ks2) << 10));
      __builtin_amdgcn_s_setprio(1);
      acc[0][0] = __builtin_amdgcn_mfma_f32_32x32x16_bf16(a0, b0, acc[0][0], 0, 0, 0);
      acc[0][1] = __builtin_amdgcn_mfma_f32_32x32x16_bf16(a1, b0, acc[0][1], 0, 0, 0);
      acc[1][0] = __builtin_amdgcn_mfma_f32_32x32x16_bf16(a0, b1, acc[1][0], 0, 0, 0);
      acc[1][1] = __builtin_amdgcn_mfma_f32_32x32x16_bf16(a1, b1, acc[1][1], 0, 0, 0);
      acc[2][0] = __builtin_amdgcn_mfma_f32_32x32x16_bf16(a0, b2, acc[2][0], 0, 0, 0);
      acc[2][1] = __builtin_amdgcn_mfma_f32_32x32x16_bf16(a1, b2, acc[2][1], 0, 0, 0);
      __builtin_amdgcn_s_setprio(0);
    }
  }

  // Epilogue. C/D layout (32x32): col n = lane&31, row = (r&3)+8*(r>>2)+4*(lane>>5).
  const int n   = n0 + wn + (lane & 31);
  const int rb  = (lane >> 5) * 4;
  const float bi  = b_ii[n] + b_hi[n];
  const float bf_ = b_if[n] + b_hf[n];
  const float bg  = b_ig[n] + b_hg[n];
#pragma unroll
  for (int i = 0; i < 2; ++i) {
#pragma unroll
    for (int r = 0; r < 16; ++r) {
      const int m = m0 + wm + i * 32 + (r & 3) + 8 * (r >> 2) + rb;
      const size_t idx = (size_t)m * HS + n;
      const float gi = acc[0][i][r] + bi;
      const float gf = acc[1][i][r] + bf_;
      const float gg = acc[2][i][r] + bg;
      const float it = 1.f / (1.f + __expf(-gi));
      const float ft = 1.f / (1.f + __expf(-gf));
      const float e2 = __expf(-2.f * gg);
      const float gt = (1.f - e2) / (1.f + e2);  // tanh
      out[idx] = ft * c[idx] + it * gt;
    }
  }
}

// ===========================================================================
// Legacy fallback — used only if workspace too small.
#define BK      32
#define NITER   (K_TOTAL / BK)

__device__ __forceinline__ void ldpanel(const float* __restrict__ src, int tid,
                                        f32x4* __restrict__ v) {
#pragma unroll
  for (int b = 0; b < 2; ++b) {
    const int cc  = tid + b * 256;
    const int row = cc >> 3;
    const int col = (cc & 7) * 4;
    v[b] = *(const f32x4*)(src + (size_t)row * HS + col);
  }
}

__device__ __forceinline__ void stpanel(bf16* __restrict__ dst, int tid,
                                        const f32x4* __restrict__ v) {
#pragma unroll
  for (int b = 0; b < 2; ++b) {
    const int cc  = tid + b * 256;
    const int row = cc >> 3;
    const int col = (cc & 7) * 4;
    bf16x4 o;
    o[0] = (bf16)v[b][0]; o[1] = (bf16)v[b][1];
    o[2] = (bf16)v[b][2]; o[3] = (bf16)v[b][3];
    *(bf16x4*)(dst + row * 32 + col) = o;
  }
}

__device__ __forceinline__ void get_srcs(
    int k, int m0, int n0,
    const float* __restrict__ x, const float* __restrict__ h,
    const float* __restrict__ w_ii, const float* __restrict__ w_hi,
    const float* __restrict__ w_if, const float* __restrict__ w_hf,
    const float* __restrict__ w_ig, const float* __restrict__ w_hg,
    const float* s[5]) {
  const int kk = k * BK;
  const float* Ag; const float* w0; const float* w1; const float* w2; int kl;
  if (kk < 1024) { Ag = x; w0 = w_ii; w1 = w_if; w2 = w_ig; kl = kk; }
  else           { Ag = h; w0 = w_hi; w1 = w_hf; w2 = w_hg; kl = kk - 1024; }
  s[0] = Ag + (size_t)m0 * HS + kl;
  s[1] = Ag + (size_t)(m0 + 64) * HS + kl;
  s[2] = w0 + (size_t)n0 * HS + kl;
  s[3] = w1 + (size_t)n0 * HS + kl;
  s[4] = w2 + (size_t)n0 * HS + kl;
}

__global__ __launch_bounds__(256, 2) void lstm_fused(
    const float* __restrict__ x, const float* __restrict__ h,
    const float* __restrict__ c,
    const float* __restrict__ w_ii, const float* __restrict__ w_hi,
    const float* __restrict__ w_if, const float* __restrict__ w_hf,
    const float* __restrict__ w_ig, const float* __restrict__ w_hg,
    const float* __restrict__ b_ii, const float* __restrict__ b_hi,
    const float* __restrict__ b_if, const float* __restrict__ b_hf,
    const float* __restrict__ b_ig, const float* __restrict__ b_hg,
    float* __restrict__ out)
{
  __shared__ bf16 smem[2 * 10240];

  const int tid  = threadIdx.x;
  const int lane = tid & 63;
  const int wave = tid >> 6;

  const int bid = blockIdx.x;
  const int nt  = bid & 15;
  const int mt  = bid >> 4;
  const int m0  = mt * 128;
  const int n0  = nt * 64;
  const int wm  = (wave & 1) * 64;
  const int wn  = (wave >> 1) * 32;

  f32x16 acc[3][2] = {};

  {
    const float* s[5];
    get_srcs(0, m0, n0, x, h, w_ii, w_hi, w_if, w_hf, w_ig, w_hg, s);
    f32x4 pf[5][2];
#pragma unroll
    for (int p = 0; p < 5; ++p) ldpanel(s[p], tid, pf[p]);
    bf16* A0 = smem;
#pragma unroll
    for (int p = 0; p < 5; ++p) stpanel(A0 + p * 2048, tid, pf[p]);
    __syncthreads();
  }

  const int fr  = lane & 31;
  const int fk8 = (lane >> 5) * 8;

  for (int k = 0; k < NITER; ++k) {
    bf16* As = smem + (k & 1) * 10240;
    bf16* Bs = As + 4096;

    f32x4 nf[5][2];
    if (k < NITER - 1) {
      const float* s[5];
      get_srcs(k + 1, m0, n0, x, h, w_ii, w_hi, w_if, w_hf, w_ig, w_hg, s);
#pragma unroll
      for (int p = 0; p < 5; ++p) ldpanel(s[p], tid, nf[p]);
    }

#pragma unroll
    for (int ks = 0; ks < 2; ++ks) {
      const int co = ks * 16 + fk8;
      bf16x8 a0 = *(const bf16x8*)(As + (wm + fr) * 32 + co);
      bf16x8 a1 = *(const bf16x8*)(As + (wm + 32 + fr) * 32 + co);
#pragma unroll
      for (int g = 0; g < 3; ++g) {
        bf16x8 b = *(const bf16x8*)(Bs + g * 2048 + (wn + fr) * 32 + co);
        acc[g][0] = __builtin_amdgcn_mfma_f32_32x32x16_bf16(a0, b, acc[g][0], 0, 0, 0);
        acc[g][1] = __builtin_amdgcn_mfma_f32_32x32x16_bf16(a1, b, acc[g][1], 0, 0, 0);
      }
    }

    if (k < NITER - 1) {
      bf16* An = smem + ((k + 1) & 1) * 10240;
#pragma unroll
      for (int p = 0; p < 5; ++p) stpanel(An + p * 2048, tid, nf[p]);
    }
    __syncthreads();
  }

  const int n   = n0 + wn + (lane & 31);
  const int rb  = (lane >> 5) * 4;
  const float bi  = b_ii[n] + b_hi[n];
  const float bf_ = b_if[n] + b_hf[n];
  const float bg  = b_ig[n] + b_hg[n];
#pragma unroll
  for (int i = 0; i < 2; ++i) {
#pragma unroll
    for (int r = 0; r < 16; ++r) {
      const int m = m0 + wm + i * 32 + (r & 3) + 8 * (r >> 2) + rb;
      const size_t idx = (size_t)m * HS + n;
      const float gi = acc[0][i][r] + bi;
      const float gf = acc[1][i][r] + bf_;
      const float gg = acc[2][i][r] + bg;
      const float it = 1.f / (1.f + __expf(-gi));
      const float ft = 1.f / (1.f + __expf(-gf));
      const float e2 = __expf(-2.f * gg);
      const float gt = (1.f - e2) / (1.f + e2);
      out[idx] = ft * c[idx] + it * gt;
    }
  }
}

// ===========================================================================
extern "C" void kernel_launch(void* const* d_in, const int* in_sizes, int n_in,
                              void* d_out, int out_size, void* d_ws, size_t ws_size,
                              hipStream_t stream) {
  const float* x  = (const float*)d_in[0];
  const float* h  = (const float*)d_in[1];
  const float* c  = (const float*)d_in[2];
  const float* w_ii = (const float*)d_in[3];
  const float* b_ii = (const float*)d_in[4];
  const float* w_hi = (const float*)d_in[5];
  const float* b_hi = (const float*)d_in[6];
  const float* w_if = (const float*)d_in[7];
  const float* b_if = (const float*)d_in[8];
  const float* w_hf = (const float*)d_in[9];
  const float* b_hf = (const float*)d_in[10];
  const float* w_ig = (const float*)d_in[11];
  const float* b_ig = (const float*)d_in[12];
  const float* w_hg = (const float*)d_in[13];
  const float* b_hg = (const float*)d_in[14];
  float* out = (float*)d_out;

  const size_t needA = (size_t)128 * A_MT_B;    // 64 MB
  const size_t needW = (size_t)16 * W_NT_B;     // 12 MB

  if (ws_size >= needA + needW) {
    bf16* Aws = (bf16*)d_ws;
    bf16* Wws = (bf16*)((char*)d_ws + needA);
    hipLaunchKernelGGL(pack_a, dim3(16384), dim3(256), 0, stream, x, h, Aws);
    hipLaunchKernelGGL(pack_w, dim3(3072), dim3(256), 0, stream,
                       w_ii, w_hi, w_if, w_hf, w_ig, w_hg, Wws);
    hipLaunchKernelGGL(lstm_gemm, dim3(2048), dim3(256), 0, stream,
                       Aws, Wws, c, b_ii, b_hi, b_if, b_hf, b_ig, b_hg, out);
  } else {
    hipLaunchKernelGGL(lstm_fused, dim3(2048), dim3(256), 0, stream,
                       x, h, c, w_ii, w_hi, w_if, w_hf, w_ig, w_hg,
                       b_ii, b_hi, b_if, b_hf, b_ig, b_hg, out);
  }
}